// Round 5
// baseline (227.307 us; speedup 1.0000x reference)
//
#include <hip/hip_runtime.h>

#define ALPHA     10.0f
#define INV_BETA  20.0f      // 1/0.05
#define FAR_DELTA 1e10f
#define NSAMP     128        // samples per ray (reference N)

__device__ __forceinline__ float laplace_density(float sdf) {
    // s = -sdf; s<=0 -> a*0.5*exp(s/b); s>0 -> a*(1-0.5*exp(-s/b))
    float s = -sdf;
    float e = __expf(-fabsf(s) * INV_BETA);
    return (s <= 0.f) ? (0.5f * ALPHA * e) : (ALPHA * (1.f - 0.5f * e));
}

// Persistent grid-stride waves, 2-deep software pipeline.
// R3/R4 post-mortem: one-shot waves stall ~97% on vmcnt (BW plateau 2.3 TB/s)
// while steady-state streaming kernels hit 6.3 TB/s on this chip. Here each
// wave processes ~8 ray-pairs and always has the NEXT pair's 5 dwordx4 loads
// in flight while computing the current one — no wave turnover, no drain.
// Half-wave (32 lanes) per ray, 4 samples per lane, registers only.
__global__ __launch_bounds__(256) void volsdf_render(
    const float* __restrict__ dist,    // [R,128]
    const float* __restrict__ color,   // [R,128,3]
    const float* __restrict__ depth,   // [R,128]
    float*       __restrict__ out,     // [R*3] color ++ [R*128*3] geometry zeros
    int R, int nWaves)
{
    const int lane = threadIdx.x & 63;
    const int sub  = lane & 31;               // sublane within half-wave
    const int half = lane >> 5;               // which ray of the pair
    const int gw   = blockIdx.x * 4 + (threadIdx.x >> 6);   // global wave id
    const int nPairs = R >> 1;

    float* geoBase = out + (size_t)R * 3;

    auto loadPair = [&](int rp, float4& di, float4& dp,
                        float4& c0, float4& c1, float4& c2) {
        const size_t rbase = (size_t)(rp * 2 + half) * NSAMP;
        di = ((const float4*)(dist  + rbase))[sub];   // 4 SDF samples
        dp = ((const float4*)(depth + rbase))[sub];   // 4 depths
        const float* cp = color + rbase * 3 + (size_t)sub * 12;
        c0 = ((const float4*)cp)[0];        // r0 g0 b0 r1
        c1 = ((const float4*)cp)[1];        // g1 b1 r2 g2
        c2 = ((const float4*)cp)[2];        // b2 r3 g3 b3
    };

    auto process = [&](int rp, float4 di, float4 dp,
                       float4 c0, float4 c1, float4 c2) {
        // Geometry zeros for this pair: 3072 B as 3 coalesced 16 B sweeps.
        // Pure stores, no dependencies — retire in the shadow of the loads.
        float4* geo = (float4*)(geoBase + (size_t)rp * 768);
        float4 z4 = make_float4(0.f, 0.f, 0.f, 0.f);
        geo[lane]       = z4;
        geo[64  + lane] = z4;
        geo[128 + lane] = z4;

        // deltas: delta[j] = depth[j+1]-depth[j]; last sample -> FAR_DELTA
        float nx  = __shfl_down(dp.x, 1, 32);
        float dl0 = dp.y - dp.x;
        float dl1 = dp.z - dp.y;
        float dl2 = dp.w - dp.z;
        float dl3 = (sub == 31) ? FAR_DELTA : (nx - dp.w);

        float d0 = laplace_density(di.x) * dl0;
        float d1 = laplace_density(di.y) * dl1;
        float d2 = laplace_density(di.z) * dl2;
        float d3 = laplace_density(di.w) * dl3;   // sub31: ~1e11, never in a used prefix

        // Width-32 exclusive scan of per-lane sums. Base via shfl_up(incl,1),
        // NOT (incl-local): sub31's ~1e11 local would cancel the O(10) base.
        float local = (d0 + d1) + (d2 + d3);
        float incl  = local;
        #pragma unroll
        for (int off = 1; off < 32; off <<= 1) {
            float v = __shfl_up(incl, off, 32);
            if (sub >= off) incl += v;
        }
        float base = __shfl_up(incl, 1, 32);
        if (sub == 0) base = 0.f;

        float p1 = base + d0, p2 = p1 + d1, p3 = p2 + d2;
        float w0 = (1.f - __expf(-d0)) * __expf(-base);
        float w1 = (1.f - __expf(-d1)) * __expf(-p1);
        float w2 = (1.f - __expf(-d2)) * __expf(-p2);
        float w3 = (1.f - __expf(-d3)) * __expf(-p3);

        // Weighted color accumulate (channel-deinterleave from 3 float4s)
        float ar = (w0 * c0.x + w1 * c0.w) + (w2 * c1.z + w3 * c2.y);
        float ag = (w0 * c0.y + w1 * c1.x) + (w2 * c1.w + w3 * c2.z);
        float ab = (w0 * c0.z + w1 * c1.y) + (w2 * c2.x + w3 * c2.w);

        // Width-32 reduction; sublane 0 of each half holds the ray's RGB.
        #pragma unroll
        for (int off = 16; off > 0; off >>= 1) {
            ar += __shfl_down(ar, off, 32);
            ag += __shfl_down(ag, off, 32);
            ab += __shfl_down(ab, off, 32);
        }
        if (sub == 0) {
            int ray = rp * 2 + half;
            out[(size_t)ray * 3 + 0] = ar;
            out[(size_t)ray * 3 + 1] = ag;
            out[(size_t)ray * 3 + 2] = ab;
        }
    };

    float4 diA, dpA, c0A, c1A, c2A;
    float4 diB, dpB, c0B, c1B, c2B;

    int rp0 = gw;
    if (rp0 >= nPairs) return;                 // wave-uniform
    loadPair(rp0, diA, dpA, c0A, c1A, c2A);

    while (true) {
        int rp1 = rp0 + nWaves;
        bool have1 = rp1 < nPairs;             // wave-uniform
        if (have1) loadPair(rp1, diB, dpB, c0B, c1B, c2B);
        process(rp0, diA, dpA, c0A, c1A, c2A); // waits only on A's loads (vmcnt(5))
        if (!have1) return;

        int rp2 = rp1 + nWaves;
        bool have2 = rp2 < nPairs;
        if (have2) loadPair(rp2, diA, dpA, c0A, c1A, c2A);
        process(rp1, diB, dpB, c0B, c1B, c2B);
        if (!have2) return;
        rp0 = rp2;
    }
}

extern "C" void kernel_launch(void* const* d_in, const int* in_sizes, int n_in,
                              void* d_out, int out_size, void* d_ws, size_t ws_size,
                              hipStream_t stream) {
    const float* dist  = (const float*)d_in[0];
    const float* color = (const float*)d_in[1];
    const float* depth = (const float*)d_in[2];
    float* out = (float*)d_out;

    const int R = in_sizes[0] / NSAMP;         // 65536
    const int nPairs = R >> 1;                 // 32768

    // Persistent: 1024 blocks = 4 blocks/CU (16 waves/CU), all resident.
    int blocks = 1024;
    int maxBlocks = (nPairs + 3) / 4;
    if (blocks > maxBlocks) blocks = maxBlocks;
    const int nWaves = blocks * 4;             // grid-stride over ray-pairs

    hipLaunchKernelGGL(volsdf_render, dim3(blocks), dim3(256), 0, stream,
                       dist, color, depth, out, R, nWaves);
}

// Round 6
// 223.898 us; speedup vs baseline: 1.0152x; 1.0152x over previous
//
#include <hip/hip_runtime.h>

#define ALPHA     10.0f
#define INV_BETA  20.0f      // 1/0.05
#define FAR_DELTA 1e10f
#define NSAMP     128        // samples per ray (reference N)

__device__ __forceinline__ float laplace_density(float sdf) {
    // s = -sdf; s<=0 -> a*0.5*exp(s/b); s>0 -> a*(1-0.5*exp(-s/b))
    float s = -sdf;
    float e = __expf(-fabsf(s) * INV_BETA);
    return (s <= 0.f) ? (0.5f * ALPHA * e) : (ALPHA * (1.f - 0.5f * e));
}

// R6: geometry zero-fill moved to hipMemsetAsync (write-only stream at fill
// speed). This kernel is now PURE READ (writes only 12 B/ray of color):
// R3/R4/R5 all plateaued at 2.3 TB/s with 5 interleaved R/W streams; the A/B
// here isolates whether the mixed R/W burst pattern was the HBM limiter.
// Half-wave (32 lanes) per ray, 4 samples per lane, registers only.
__global__ __launch_bounds__(256) void volsdf_render(
    const float* __restrict__ dist,    // [R,128]
    const float* __restrict__ color,   // [R,128,3]
    const float* __restrict__ depth,   // [R,128]
    float*       __restrict__ out,     // [R*3] ray colors (geometry pre-zeroed)
    int R)
{
    const int lane   = threadIdx.x & 63;
    const int waveId = threadIdx.x >> 6;
    const int sub    = lane & 31;              // sublane within half-wave
    const int half   = lane >> 5;              // which ray of the pair
    const int rayPair = blockIdx.x * 4 + waveId;
    const int ray     = rayPair * 2 + half;
    if (ray >= R) return;                      // wave-uniform for R % 8 == 0

    const size_t rbase = (size_t)ray * NSAMP;

    // ---- Issue ALL loads first: 5x global_load_dwordx4 in flight ----
    float4 di = ((const float4*)(dist  + rbase))[sub];   // 4 SDF samples
    float4 dp = ((const float4*)(depth + rbase))[sub];   // 4 depths
    const float* cp = color + rbase * 3 + (size_t)sub * 12;
    float4 c0 = ((const float4*)cp)[0];        // r0 g0 b0 r1
    float4 c1 = ((const float4*)cp)[1];        // g1 b1 r2 g2
    float4 c2 = ((const float4*)cp)[2];        // b2 r3 g3 b3

    // ---- deltas: delta[j] = depth[j+1]-depth[j]; last sample -> FAR_DELTA
    float nx  = __shfl_down(dp.x, 1, 32);      // next sublane's first depth
    float dl0 = dp.y - dp.x;
    float dl1 = dp.z - dp.y;
    float dl2 = dp.w - dp.z;
    float dl3 = (sub == 31) ? FAR_DELTA : (nx - dp.w);

    float d0 = laplace_density(di.x) * dl0;
    float d1 = laplace_density(di.y) * dl1;
    float d2 = laplace_density(di.z) * dl2;
    float d3 = laplace_density(di.w) * dl3;    // sub31: ~1e11, never in a used prefix

    // ---- width-32 exclusive scan of per-lane sums (5 steps).
    // Base via shfl_up(incl,1), NOT (incl-local): sub31's ~1e11 local would
    // catastrophically cancel the O(10) base (R1 bug).
    float local = (d0 + d1) + (d2 + d3);
    float incl  = local;
    #pragma unroll
    for (int off = 1; off < 32; off <<= 1) {
        float v = __shfl_up(incl, off, 32);
        if (sub >= off) incl += v;
    }
    float base = __shfl_up(incl, 1, 32);
    if (sub == 0) base = 0.f;

    float p1 = base + d0, p2 = p1 + d1, p3 = p2 + d2;
    float w0 = (1.f - __expf(-d0)) * __expf(-base);
    float w1 = (1.f - __expf(-d1)) * __expf(-p1);
    float w2 = (1.f - __expf(-d2)) * __expf(-p2);
    float w3 = (1.f - __expf(-d3)) * __expf(-p3);

    // ---- weighted color accumulate (channel-deinterleave from 3 float4s)
    float ar = (w0 * c0.x + w1 * c0.w) + (w2 * c1.z + w3 * c2.y);
    float ag = (w0 * c0.y + w1 * c1.x) + (w2 * c1.w + w3 * c2.z);
    float ab = (w0 * c0.z + w1 * c1.y) + (w2 * c2.x + w3 * c2.w);

    // ---- width-32 reduction (5 steps); sublane 0 of each half holds the sum
    #pragma unroll
    for (int off = 16; off > 0; off >>= 1) {
        ar += __shfl_down(ar, off, 32);
        ag += __shfl_down(ag, off, 32);
        ab += __shfl_down(ab, off, 32);
    }
    if (sub == 0) {
        out[(size_t)ray * 3 + 0] = ar;
        out[(size_t)ray * 3 + 1] = ag;
        out[(size_t)ray * 3 + 2] = ab;
    }
}

extern "C" void kernel_launch(void* const* d_in, const int* in_sizes, int n_in,
                              void* d_out, int out_size, void* d_ws, size_t ws_size,
                              hipStream_t stream) {
    const float* dist  = (const float*)d_in[0];
    const float* color = (const float*)d_in[1];
    const float* depth = (const float*)d_in[2];
    float* out = (float*)d_out;

    const int R = in_sizes[0] / NSAMP;         // 65536
    const int blocks = (R + 7) / 8;            // 8 rays per 256-thread block

    // Zero the whole output (geometry zeros + color region, overwritten by
    // the kernel). Write-only fill stream — graph-capturable memset node.
    hipMemsetAsync(d_out, 0, (size_t)out_size * sizeof(float), stream);

    hipLaunchKernelGGL(volsdf_render, dim3(blocks), dim3(256), 0, stream,
                       dist, color, depth, out, R);
}